// Round 3
// baseline (203.373 us; speedup 1.0000x reference)
//
#include <hip/hip_runtime.h>
#include <hip/hip_bf16.h>

#define N 4096
#define D 768

typedef __bf16 bf16x8 __attribute__((ext_vector_type(8)));
typedef float f32x4 __attribute__((ext_vector_type(4)));

// ---------------- normalize: f32 [N][D] -> bf16 [N][D], row L2-normalized ----
__global__ __launch_bounds__(256) void norm4(const float* __restrict__ x0,
                                             const float* __restrict__ x1,
                                             const float* __restrict__ x2,
                                             const float* __restrict__ x3,
                                             __hip_bfloat16* __restrict__ o) {
    int a = blockIdx.y;
    const float* x = (a == 0) ? x0 : (a == 1) ? x1 : (a == 2) ? x2 : x3;
    __hip_bfloat16* out = o + (size_t)a * N * D;
    int row = blockIdx.x;
    const float* xr = x + (size_t)row * D;
    int t = threadIdx.x;
    float v0 = xr[t], v1 = xr[t + 256], v2 = xr[t + 512];
    float ss = v0 * v0 + v1 * v1 + v2 * v2;
    #pragma unroll
    for (int m = 1; m < 64; m <<= 1) ss += __shfl_xor(ss, m);
    __shared__ float red[4];
    int lane = t & 63, wid = t >> 6;
    if (lane == 0) red[wid] = ss;
    __syncthreads();
    float tot = red[0] + red[1] + red[2] + red[3];
    float scale = 1.0f / fmaxf(sqrtf(tot), 1e-8f);
    __hip_bfloat16* orow = out + (size_t)row * D;
    orow[t]       = __float2bfloat16(v0 * scale);
    orow[t + 256] = __float2bfloat16(v1 * scale);
    orow[t + 512] = __float2bfloat16(v2 * scale);
}

// ---------------- fused dual-GEMM + softmax-KL partial stats -----------------
// Direct-from-L2 design: NO LDS in the K-loop, no barriers, no staging.
// Block 128x128, 4 waves (2x2), wave tile 64x64 per gemm (s and t).
// Each lane loads its MFMA fragment straight from global memory:
//   A-frag m: row i0+wm*64+m*16+(lane&15), bytes [kt*64 + (lane>>4)*16 .. +16)
// -> 16 global_load_dwordx4 + 32 MFMA per K-step, pure dataflow.
// Inputs (24 MB total) are L2/L3 resident; intra-block reuse is only 2x so
// LDS staging bought little and cost barriers + LDS pipe time.

__global__ __launch_bounds__(256, 2) void fused_gemm(
        const __hip_bfloat16* __restrict__ Xs, const __hip_bfloat16* __restrict__ Ys,
        const __hip_bfloat16* __restrict__ Xt, const __hip_bfloat16* __restrict__ Yt,
        float* __restrict__ partial) {
    // bijective XCD-chunked swizzle: 1024 blocks = 8 XCDs x 128; each XCD gets
    // 4 consecutive ib-rows (A-panel L2 locality), B K-front shared device-wide
    int bid = blockIdx.x;
    int nid = (bid & 7) * 128 + (bid >> 3);
    int ib = nid >> 5, jb = nid & 31;
    int i0 = ib * 128, j0 = jb * 128;

    int t = threadIdx.x;
    int lane = t & 63, wid = t >> 6;
    int wm = wid >> 1, wn = wid & 1;
    int row16 = lane & 15, kc = lane >> 4;

    const int ROWB = D * 2;            // 1536 bytes per row
    const int FRAG = 16 * ROWB;        // 16-row stride between m-frags

    size_t offA = (size_t)(i0 + wm * 64 + row16) * ROWB + kc * 16;
    size_t offB = (size_t)(j0 + wn * 64 + row16) * ROWB + kc * 16;
    const char* axs = (const char*)Xs + offA;
    const char* axt = (const char*)Xt + offA;
    const char* bys = (const char*)Ys + offB;
    const char* byt = (const char*)Yt + offB;

    f32x4 acc_s[4][4] = {};
    f32x4 acc_t[4][4] = {};

    #pragma unroll 2
    for (int kt = 0; kt < D / 32; ++kt) {
        bf16x8 a_s[4], a_t[4], b_s[4], b_t[4];
        #pragma unroll
        for (int m = 0; m < 4; ++m) {
            a_s[m] = *(const bf16x8*)(axs + m * FRAG);
            a_t[m] = *(const bf16x8*)(axt + m * FRAG);
            b_s[m] = *(const bf16x8*)(bys + m * FRAG);
            b_t[m] = *(const bf16x8*)(byt + m * FRAG);
        }
        #pragma unroll
        for (int m = 0; m < 4; ++m)
            #pragma unroll
            for (int n = 0; n < 4; ++n) {
                acc_s[m][n] = __builtin_amdgcn_mfma_f32_16x16x32_bf16(a_s[m], b_s[n], acc_s[m][n], 0, 0, 0);
                acc_t[m][n] = __builtin_amdgcn_mfma_f32_16x16x32_bf16(a_t[m], b_t[n], acc_t[m][n], 0, 0, 0);
            }
        axs += 64; axt += 64; bys += 64; byt += 64;
    }

    // ---- epilogue: per-row partial stats over this block's 128 columns ----
    __shared__ float part[2 * 128 * 4];   // [wn][128 rows][4 stats]
    int g = lane >> 4, cl = lane & 15;

    #pragma unroll
    for (int m = 0; m < 4; ++m) {
        float st[4][4];              // [reg][stat]
        #pragma unroll
        for (int r = 0; r < 4; ++r) { st[r][0] = 0.f; st[r][1] = 0.f; st[r][2] = 0.f; st[r][3] = 0.f; }
        #pragma unroll
        for (int n = 0; n < 4; ++n)
            #pragma unroll
            for (int r = 0; r < 4; ++r) {
                float ls = 10.0f * acc_s[m][n][r];
                float lt = 10.0f * acc_t[m][n][r];
                float es = __expf(ls - 10.0f);
                float et = __expf(lt - 10.0f);
                st[r][0] += es;
                st[r][1] += et;
                st[r][2] += es * (ls - lt);
                st[r][3] += et * (lt - ls);
            }
        #pragma unroll
        for (int r = 0; r < 4; ++r)
            #pragma unroll
            for (int s = 0; s < 4; ++s) {
                float v = st[r][s];
                v += __shfl_xor(v, 1);
                v += __shfl_xor(v, 2);
                v += __shfl_xor(v, 4);
                v += __shfl_xor(v, 8);
                st[r][s] = v;
            }
        if (cl == 0) {
            int row = wm * 64 + m * 16 + g * 4;
            #pragma unroll
            for (int r = 0; r < 4; ++r)
                #pragma unroll
                for (int s = 0; s < 4; ++s)
                    part[(wn * 128 + row + r) * 4 + s] = st[r][s];
        }
    }
    __syncthreads();
    #pragma unroll
    for (int q = 0; q < 2; ++q) {
        int idx = t + q * 256;       // 512 slots = 128 rows x 4 stats
        int row = idx >> 2, s = idx & 3;
        float v = part[(0 * 128 + row) * 4 + s] + part[(1 * 128 + row) * 4 + s];
        partial[((size_t)jb * N + (i0 + row)) * 4 + s] = v;
    }
}

// ---------------- per-row finalize + block partial sums ----------------------
__global__ __launch_bounds__(256) void reduce_rows(const float* __restrict__ partial,
                                                   float* __restrict__ blocksum) {
    int row = blockIdx.x * 256 + threadIdx.x;
    float zs = 0.f, zt = 0.f, ws = 0.f, wt = 0.f;
    for (int jb = 0; jb < 32; ++jb) {
        const float* p = partial + ((size_t)jb * N + row) * 4;
        zs += p[0]; zt += p[1]; ws += p[2]; wt += p[3];
    }
    float ls_row = wt / zt - logf(zt) + logf(zs);   // sum_j q_t (log q_t - log q_s)
    float lt_row = ws / zs - logf(zs) + logf(zt);   // sum_j q_s (log q_s - log q_t)
    #pragma unroll
    for (int m = 1; m < 64; m <<= 1) {
        ls_row += __shfl_xor(ls_row, m);
        lt_row += __shfl_xor(lt_row, m);
    }
    __shared__ float rs[4], rt[4];
    int lane = threadIdx.x & 63, wid = threadIdx.x >> 6;
    if (lane == 0) { rs[wid] = ls_row; rt[wid] = lt_row; }
    __syncthreads();
    if (threadIdx.x == 0) {
        blocksum[blockIdx.x * 2]     = rs[0] + rs[1] + rs[2] + rs[3];
        blocksum[blockIdx.x * 2 + 1] = rt[0] + rt[1] + rt[2] + rt[3];
    }
}

__global__ void final_reduce(const float* __restrict__ blocksum, float* __restrict__ out) {
    float a = 0.f, b = 0.f;
    if (threadIdx.x < 16) { a = blocksum[threadIdx.x * 2]; b = blocksum[threadIdx.x * 2 + 1]; }
    #pragma unroll
    for (int m = 1; m < 16; m <<= 1) { a += __shfl_xor(a, m); b += __shfl_xor(b, m); }
    if (threadIdx.x == 0) {
        const float inv = 1.0f / 16777216.0f;   // 1/N^2
        out[0] = a * inv;
        out[1] = b * inv;
    }
}

extern "C" void kernel_launch(void* const* d_in, const int* in_sizes, int n_in,
                              void* d_out, int out_size, void* d_ws, size_t ws_size,
                              hipStream_t stream) {
    const float* zxs = (const float*)d_in[0];
    const float* zys = (const float*)d_in[1];
    const float* zxt = (const float*)d_in[2];
    const float* zyt = (const float*)d_in[3];

    char* ws = (char*)d_ws;
    const size_t A = (size_t)N * D * 2;               // bytes per bf16 array
    __hip_bfloat16* nb = (__hip_bfloat16*)ws;         // 4 normalized bf16 arrays
    float* partial  = (float*)(ws + 4 * A);           // [32][N][4] f32 = 2 MB
    float* blocksum = (float*)(ws + 4 * A + (size_t)32 * N * 4 * sizeof(float));

    norm4<<<dim3(N, 4), 256, 0, stream>>>(zxs, zys, zxt, zyt, nb);

    const __hip_bfloat16* Xs = nb;
    const __hip_bfloat16* Ys = nb + (size_t)N * D;
    const __hip_bfloat16* Xt = nb + 2 * (size_t)N * D;
    const __hip_bfloat16* Yt = nb + 3 * (size_t)N * D;
    fused_gemm<<<dim3(1024), 256, 0, stream>>>(Xs, Ys, Xt, Yt, partial);

    reduce_rows<<<16, 256, 0, stream>>>(partial, blocksum);
    final_reduce<<<1, 64, 0, stream>>>(blocksum, (float*)d_out);
}

// Round 4
// 91.204 us; speedup vs baseline: 2.2299x; 2.2299x over previous
//
#include <hip/hip_runtime.h>
#include <hip/hip_bf16.h>

#define N 4096
#define D 768
#define NK 24   // D/32 K-steps

typedef float f32x4 __attribute__((ext_vector_type(4)));

typedef __attribute__((address_space(3))) unsigned int as3_uint;
typedef const __attribute__((address_space(1))) unsigned int as1_uint;

__device__ __forceinline__ void gload16(const void* g, void* l) {
    __builtin_amdgcn_global_load_lds((as1_uint*)g, (as3_uint*)l, 16, 0, 0);
}

__device__ __forceinline__ unsigned char f2fp8(float v) {
    // v_cvt_pk_fp8_f32; on gfx950 HW fp8 is OCP e4m3 — consistent with MFMA
    return (unsigned char)(__builtin_amdgcn_cvt_pk_fp8_f32(v, v, 0, false) & 0xff);
}

// ---------------- normalize: f32 [N][D] -> fp8 [N][D], row L2-normalized ----
__global__ __launch_bounds__(256) void norm4(const float* __restrict__ x0,
                                             const float* __restrict__ x1,
                                             const float* __restrict__ x2,
                                             const float* __restrict__ x3,
                                             unsigned char* __restrict__ o) {
    int a = blockIdx.y;
    const float* x = (a == 0) ? x0 : (a == 1) ? x1 : (a == 2) ? x2 : x3;
    unsigned char* out = o + (size_t)a * N * D;
    int row = blockIdx.x;
    const float* xr = x + (size_t)row * D;
    int t = threadIdx.x;
    float v0 = xr[t], v1 = xr[t + 256], v2 = xr[t + 512];
    float ss = v0 * v0 + v1 * v1 + v2 * v2;
    #pragma unroll
    for (int m = 1; m < 64; m <<= 1) ss += __shfl_xor(ss, m);
    __shared__ float red[4];
    int lane = t & 63, wid = t >> 6;
    if (lane == 0) red[wid] = ss;
    __syncthreads();
    float tot = red[0] + red[1] + red[2] + red[3];
    float scale = 1.0f / fmaxf(sqrtf(tot), 1e-8f);
    unsigned char* orow = out + (size_t)row * D;
    orow[t]       = f2fp8(v0 * scale);
    orow[t + 256] = f2fp8(v1 * scale);
    orow[t + 512] = f2fp8(v2 * scale);
}

// ---------------- fused dual-GEMM (fp8) + softmax-KL partial stats -----------
// Tile 128x128, BK=32, 4 waves (2x2), wave tile 64x64 per gemm.
// LDS buffer (16KB) = As,At,Bs,Bt tiles of 128x32 fp8 (4KB each); double-buffered.
// Schedule: 2 phases per K-step (S-gemm, T-gemm). Each phase:
//   s_waitcnt vmcnt(2); s_barrier; ds_read frags; issue 2 global_load_lds for
//   the NEXT K-step's same-pair tiles; setprio(1); 16 MFMA; setprio(0).
// Issue order [s@k, t@k, s@k+1, t@k+1, ...] makes vmcnt(2) exactly drain this
// phase's tiles while keeping the other pair in flight — no vmcnt(0) in loop.

__global__ __launch_bounds__(256, 2) void fused_gemm(
        const unsigned char* __restrict__ Xs, const unsigned char* __restrict__ Ys,
        const unsigned char* __restrict__ Xt, const unsigned char* __restrict__ Yt,
        float* __restrict__ partial) {
    __shared__ __align__(16) char smem[32768];
    const int t = threadIdx.x;
    const int jb = blockIdx.x, ib = blockIdx.y;
    const int i0 = ib * 128, j0 = jb * 128;
    const int lane = t & 63, wid = t >> 6;
    const int wm = wid >> 1, wn = wid & 1;
    const int l15 = lane & 15, kc = lane >> 4;

    f32x4 acc_s[4][4] = {};
    f32x4 acc_t[4][4] = {};

    // staging sources: thread t covers tile row t>>1, 16B chunk (t&1)
    const int srow = t >> 1, scol = (t & 1) << 4;
    const unsigned char* gAs = Xs + (size_t)(i0 + srow) * D + scol;
    const unsigned char* gAt = Xt + (size_t)(i0 + srow) * D + scol;
    const unsigned char* gBs = Ys + (size_t)(j0 + srow) * D + scol;
    const unsigned char* gBt = Yt + (size_t)(j0 + srow) * D + scol;

    char* cur = smem;            // tiles: As @0, At @4096, Bs @8192, Bt @12288
    char* nxt = smem + 16384;
    const int sdst = t * 16;

    // prologue: K-step 0, s-pair first then t-pair (issue order matters!)
    gload16(gAs, cur + sdst);
    gload16(gBs, cur + 8192 + sdst);
    gload16(gAt, cur + 4096 + sdst);
    gload16(gBt, cur + 12288 + sdst);
    gAs += 32; gBs += 32; gAt += 32; gBt += 32;

    const int rA = (wm * 64 + l15) * 32 + kc * 8;  // frag byte offsets in tile
    const int rB = (wn * 64 + l15) * 32 + kc * 8;

    long a[4], b[4];
    #pragma unroll 1
    for (int kt = 0; kt < NK - 1; ++kt) {
        // ---------------- phase S ----------------
        asm volatile("s_waitcnt vmcnt(2)" ::: "memory");
        __builtin_amdgcn_s_barrier();
        asm volatile("" ::: "memory");
        #pragma unroll
        for (int m = 0; m < 4; ++m) a[m] = *(const long*)(cur + rA + m * 512);
        #pragma unroll
        for (int n = 0; n < 4; ++n) b[n] = *(const long*)(cur + 8192 + rB + n * 512);
        gload16(gAs, nxt + sdst);
        gload16(gBs, nxt + 8192 + sdst);
        gAs += 32; gBs += 32;
        __builtin_amdgcn_s_setprio(1);
        #pragma unroll
        for (int m = 0; m < 4; ++m)
            #pragma unroll
            for (int n = 0; n < 4; ++n)
                acc_s[m][n] = __builtin_amdgcn_mfma_f32_16x16x32_fp8_fp8(a[m], b[n], acc_s[m][n], 0, 0, 0);
        __builtin_amdgcn_s_setprio(0);

        // ---------------- phase T ----------------
        asm volatile("s_waitcnt vmcnt(2)" ::: "memory");
        __builtin_amdgcn_s_barrier();
        asm volatile("" ::: "memory");
        #pragma unroll
        for (int m = 0; m < 4; ++m) a[m] = *(const long*)(cur + 4096 + rA + m * 512);
        #pragma unroll
        for (int n = 0; n < 4; ++n) b[n] = *(const long*)(cur + 12288 + rB + n * 512);
        gload16(gAt, nxt + 4096 + sdst);
        gload16(gBt, nxt + 12288 + sdst);
        gAt += 32; gBt += 32;
        __builtin_amdgcn_s_setprio(1);
        #pragma unroll
        for (int m = 0; m < 4; ++m)
            #pragma unroll
            for (int n = 0; n < 4; ++n)
                acc_t[m][n] = __builtin_amdgcn_mfma_f32_16x16x32_fp8_fp8(a[m], b[n], acc_t[m][n], 0, 0, 0);
        __builtin_amdgcn_s_setprio(0);

        char* tmp = cur; cur = nxt; nxt = tmp;
    }

    // peeled last K-step (no staging)
    asm volatile("s_waitcnt vmcnt(2)" ::: "memory");
    __builtin_amdgcn_s_barrier();
    asm volatile("" ::: "memory");
    #pragma unroll
    for (int m = 0; m < 4; ++m) a[m] = *(const long*)(cur + rA + m * 512);
    #pragma unroll
    for (int n = 0; n < 4; ++n) b[n] = *(const long*)(cur + 8192 + rB + n * 512);
    __builtin_amdgcn_s_setprio(1);
    #pragma unroll
    for (int m = 0; m < 4; ++m)
        #pragma unroll
        for (int n = 0; n < 4; ++n)
            acc_s[m][n] = __builtin_amdgcn_mfma_f32_16x16x32_fp8_fp8(a[m], b[n], acc_s[m][n], 0, 0, 0);
    __builtin_amdgcn_s_setprio(0);

    asm volatile("s_waitcnt vmcnt(0)" ::: "memory");
    __builtin_amdgcn_s_barrier();
    asm volatile("" ::: "memory");
    #pragma unroll
    for (int m = 0; m < 4; ++m) a[m] = *(const long*)(cur + 4096 + rA + m * 512);
    #pragma unroll
    for (int n = 0; n < 4; ++n) b[n] = *(const long*)(cur + 12288 + rB + n * 512);
    __builtin_amdgcn_s_setprio(1);
    #pragma unroll
    for (int m = 0; m < 4; ++m)
        #pragma unroll
        for (int n = 0; n < 4; ++n)
            acc_t[m][n] = __builtin_amdgcn_mfma_f32_16x16x32_fp8_fp8(a[m], b[n], acc_t[m][n], 0, 0, 0);
    __builtin_amdgcn_s_setprio(0);

    // ---- epilogue: per-row partial stats over this block's 128 columns ----
    __syncthreads();
    float* part = (float*)smem;      // [2 wn][128 rows][4 stats]
    int g = lane >> 4, cl = lane & 15;

    #pragma unroll
    for (int m = 0; m < 4; ++m) {
        float st[4][4];
        #pragma unroll
        for (int r = 0; r < 4; ++r) { st[r][0] = 0.f; st[r][1] = 0.f; st[r][2] = 0.f; st[r][3] = 0.f; }
        #pragma unroll
        for (int n = 0; n < 4; ++n)
            #pragma unroll
            for (int r = 0; r < 4; ++r) {
                float ls = 10.0f * acc_s[m][n][r];
                float lt = 10.0f * acc_t[m][n][r];
                float es = __expf(ls - 10.0f);
                float et = __expf(lt - 10.0f);
                st[r][0] += es;
                st[r][1] += et;
                st[r][2] += es * (ls - lt);
                st[r][3] += et * (lt - ls);
            }
        #pragma unroll
        for (int r = 0; r < 4; ++r)
            #pragma unroll
            for (int s = 0; s < 4; ++s) {
                float v = st[r][s];
                v += __shfl_xor(v, 1);
                v += __shfl_xor(v, 2);
                v += __shfl_xor(v, 4);
                v += __shfl_xor(v, 8);
                st[r][s] = v;
            }
        if (cl == 0) {
            int row = wm * 64 + m * 16 + g * 4;
            #pragma unroll
            for (int r = 0; r < 4; ++r)
                #pragma unroll
                for (int s = 0; s < 4; ++s)
                    part[(wn * 128 + row + r) * 4 + s] = st[r][s];
        }
    }
    __syncthreads();
    #pragma unroll
    for (int q = 0; q < 2; ++q) {
        int idx = t + q * 256;
        int row = idx >> 2, s = idx & 3;
        float v = part[(0 * 128 + row) * 4 + s] + part[(1 * 128 + row) * 4 + s];
        partial[((size_t)jb * N + (i0 + row)) * 4 + s] = v;
    }
}

// ---------------- per-row finalize + block partial sums ----------------------
__global__ __launch_bounds__(256) void reduce_rows(const float* __restrict__ partial,
                                                   float* __restrict__ blocksum) {
    int row = blockIdx.x * 256 + threadIdx.x;
    float zs = 0.f, zt = 0.f, ws = 0.f, wt = 0.f;
    for (int jb = 0; jb < 32; ++jb) {
        const float* p = partial + ((size_t)jb * N + row) * 4;
        zs += p[0]; zt += p[1]; ws += p[2]; wt += p[3];
    }
    float ls_row = wt / zt - logf(zt) + logf(zs);
    float lt_row = ws / zs - logf(zs) + logf(zt);
    #pragma unroll
    for (int m = 1; m < 64; m <<= 1) {
        ls_row += __shfl_xor(ls_row, m);
        lt_row += __shfl_xor(lt_row, m);
    }
    __shared__ float rs[4], rt[4];
    int lane = threadIdx.x & 63, wid = threadIdx.x >> 6;
    if (lane == 0) { rs[wid] = ls_row; rt[wid] = lt_row; }
    __syncthreads();
    if (threadIdx.x == 0) {
        blocksum[blockIdx.x * 2]     = rs[0] + rs[1] + rs[2] + rs[3];
        blocksum[blockIdx.x * 2 + 1] = rt[0] + rt[1] + rt[2] + rt[3];
    }
}

__global__ void final_reduce(const float* __restrict__ blocksum, float* __restrict__ out) {
    float a = 0.f, b = 0.f;
    if (threadIdx.x < 16) { a = blocksum[threadIdx.x * 2]; b = blocksum[threadIdx.x * 2 + 1]; }
    #pragma unroll
    for (int m = 1; m < 16; m <<= 1) { a += __shfl_xor(a, m); b += __shfl_xor(b, m); }
    if (threadIdx.x == 0) {
        const float inv = 1.0f / 16777216.0f;   // 1/N^2
        out[0] = a * inv;
        out[1] = b * inv;
    }
}

extern "C" void kernel_launch(void* const* d_in, const int* in_sizes, int n_in,
                              void* d_out, int out_size, void* d_ws, size_t ws_size,
                              hipStream_t stream) {
    const float* zxs = (const float*)d_in[0];
    const float* zys = (const float*)d_in[1];
    const float* zxt = (const float*)d_in[2];
    const float* zyt = (const float*)d_in[3];

    char* ws = (char*)d_ws;
    const size_t A = (size_t)N * D;                   // bytes per fp8 array
    unsigned char* nb = (unsigned char*)ws;           // 4 normalized fp8 arrays
    float* partial  = (float*)(ws + 4 * A);           // [32][N][4] f32 = 2 MB
    float* blocksum = (float*)(ws + 4 * A + (size_t)32 * N * 4 * sizeof(float));

    norm4<<<dim3(N, 4), 256, 0, stream>>>(zxs, zys, zxt, zyt, nb);

    const unsigned char* Xs = nb;
    const unsigned char* Ys = nb + A;
    const unsigned char* Xt = nb + 2 * A;
    const unsigned char* Yt = nb + 3 * A;
    fused_gemm<<<dim3(32, 32), 256, 0, stream>>>(Xs, Ys, Xt, Yt, partial);

    reduce_rows<<<16, 256, 0, stream>>>(partial, blocksum);
    final_reduce<<<1, 64, 0, stream>>>(blocksum, (float*)d_out);
}

// Round 5
// 64.017 us; speedup vs baseline: 3.1769x; 1.4247x over previous
//
#include <hip/hip_runtime.h>
#include <hip/hip_bf16.h>

#define N 4096
#define D 768
#define NK 24   // D/32 K-steps

typedef float f32x4 __attribute__((ext_vector_type(4)));
typedef unsigned long u64x2 __attribute__((ext_vector_type(2)));

typedef __attribute__((address_space(3))) unsigned int as3_uint;
typedef const __attribute__((address_space(1))) unsigned int as1_uint;

__device__ __forceinline__ void gload16(const void* g, void* l) {
    __builtin_amdgcn_global_load_lds((as1_uint*)g, (as3_uint*)l, 16, 0, 0);
}

// Tiled fp8 global layout (per array, per 32-row group = 24 tiles x 1024B):
//   addr(R,k) = ((R>>5)*24 + k/32)*1024 + ((R&15) + 16*((k%32)>>3))*16
//             + ((R>>4)&1)*8 + (k&7)
// i.e. within a 1024B tile: byte = l*16 + h*8 + ko, l = (R%16) + 16*kc.
// Staging thread t copies 16B (lane-linear dest) and lands frag-pair
// interleaved data; fragment reads are ds_read_b128 at base + lane*16
// (bank-uniform, conflict-free), each yielding TWO mfma operands.

// ---------------- normalize: f32 [N][D] -> fp8 tiled, row L2-normalized ------
__global__ __launch_bounds__(256) void norm4(const float* __restrict__ x0,
                                             const float* __restrict__ x1,
                                             const float* __restrict__ x2,
                                             const float* __restrict__ x3,
                                             unsigned char* __restrict__ o) {
    int a = blockIdx.y;
    const float* x = (a == 0) ? x0 : (a == 1) ? x1 : (a == 2) ? x2 : x3;
    unsigned char* out = o + (size_t)a * N * D;
    int i0 = blockIdx.x * 32;                 // 32-row group
    __shared__ __align__(16) unsigned char tile[24576];
    int t = threadIdx.x, lane = t & 63, w = t >> 6;

    for (int rr = 0; rr < 8; ++rr) {
        int R = i0 + w * 8 + rr;
        const f32x4* xr = (const f32x4*)(x + (size_t)R * D);
        // lane handles granule g0 = lane (k=8*lane..+8); lanes<32 also g1 = 64+lane
        f32x4 v0 = xr[lane * 2], v1 = xr[lane * 2 + 1];
        f32x4 v2 = {}, v3 = {};
        if (lane < 32) { v2 = xr[128 + lane * 2]; v3 = xr[128 + lane * 2 + 1]; }
        float ss = v0[0]*v0[0] + v0[1]*v0[1] + v0[2]*v0[2] + v0[3]*v0[3]
                 + v1[0]*v1[0] + v1[1]*v1[1] + v1[2]*v1[2] + v1[3]*v1[3]
                 + v2[0]*v2[0] + v2[1]*v2[1] + v2[2]*v2[2] + v2[3]*v2[3]
                 + v3[0]*v3[0] + v3[1]*v3[1] + v3[2]*v3[2] + v3[3]*v3[3];
        #pragma unroll
        for (int m = 1; m < 64; m <<= 1) ss += __shfl_xor(ss, m);
        float s = 1.0f / fmaxf(sqrtf(ss), 1e-8f);

        // pack granule -> 8B at tiled LDS position (only word0/low-16 path)
        {
            unsigned int wlo = __builtin_amdgcn_cvt_pk_fp8_f32(v0[0]*s, v0[1]*s, 0, false) & 0xffff;
            unsigned int whi = __builtin_amdgcn_cvt_pk_fp8_f32(v0[2]*s, v0[3]*s, 0, false) & 0xffff;
            unsigned int w0 = wlo | (whi << 16);
            wlo = __builtin_amdgcn_cvt_pk_fp8_f32(v1[0]*s, v1[1]*s, 0, false) & 0xffff;
            whi = __builtin_amdgcn_cvt_pk_fp8_f32(v1[2]*s, v1[3]*s, 0, false) & 0xffff;
            unsigned int w1 = wlo | (whi << 16);
            int g = lane;
            int off = (g >> 2) * 1024 + ((R & 15) + ((g & 3) << 4)) * 16 + (((R >> 4) & 1) << 3);
            *(uint2*)(tile + off) = make_uint2(w0, w1);
        }
        if (lane < 32) {
            unsigned int wlo = __builtin_amdgcn_cvt_pk_fp8_f32(v2[0]*s, v2[1]*s, 0, false) & 0xffff;
            unsigned int whi = __builtin_amdgcn_cvt_pk_fp8_f32(v2[2]*s, v2[3]*s, 0, false) & 0xffff;
            unsigned int w0 = wlo | (whi << 16);
            wlo = __builtin_amdgcn_cvt_pk_fp8_f32(v3[0]*s, v3[1]*s, 0, false) & 0xffff;
            whi = __builtin_amdgcn_cvt_pk_fp8_f32(v3[2]*s, v3[3]*s, 0, false) & 0xffff;
            unsigned int w1 = wlo | (whi << 16);
            int g = 64 + lane;
            int off = (g >> 2) * 1024 + ((R & 15) + ((g & 3) << 4)) * 16 + (((R >> 4) & 1) << 3);
            *(uint2*)(tile + off) = make_uint2(w0, w1);
        }
    }
    __syncthreads();
    // coalesced 24KB flush
    unsigned char* dst = out + (size_t)(i0 >> 5) * 24576;
    #pragma unroll
    for (int i = 0; i < 6; ++i)
        ((int4*)dst)[t + i * 256] = ((const int4*)tile)[t + i * 256];
}

// ---------------- fused dual-GEMM (fp8, tiled) + softmax-KL partials ---------
// 128x128 tile, BK=32, 4 waves (2x2), wave tile 64x64 per gemm.
// LDS: As@0 At@4096 Bs@8192 Bt@12288 (4KB each), double-buffered (32KB).
// 2 phases/K-step with counted vmcnt(2) (R4-verified schedule).

__global__ __launch_bounds__(256, 2) void fused_gemm(
        const unsigned char* __restrict__ Xs, const unsigned char* __restrict__ Ys,
        const unsigned char* __restrict__ Xt, const unsigned char* __restrict__ Yt,
        float* __restrict__ partial) {
    __shared__ __align__(16) char smem[32768];
    const int t = threadIdx.x;
    const int jb = blockIdx.x, ib = blockIdx.y;
    const int i0 = ib * 128;
    const int lane = t & 63, wid = t >> 6;
    const int wm = wid >> 1, wn = wid & 1;

    f32x4 acc_s[4][4] = {};
    f32x4 acc_t[4][4] = {};

    const size_t srcA = ((size_t)(ib * 4 + (t >> 6))) * 24576 + (size_t)(t & 63) * 16;
    const size_t srcB = ((size_t)(jb * 4 + (t >> 6))) * 24576 + (size_t)(t & 63) * 16;
    const unsigned char* gAs = Xs + srcA;
    const unsigned char* gAt = Xt + srcA;
    const unsigned char* gBs = Ys + srcB;
    const unsigned char* gBt = Yt + srcB;

    char* cur = smem;
    char* nxt = smem + 16384;
    const int sdst = t * 16;

    // prologue: K-step 0, s-pair first then t-pair (vmcnt issue order!)
    gload16(gAs, cur + sdst);
    gload16(gBs, cur + 8192 + sdst);
    gload16(gAt, cur + 4096 + sdst);
    gload16(gBt, cur + 12288 + sdst);
    gAs += 1024; gBs += 1024; gAt += 1024; gBt += 1024;

    const int offA = wm * 2048 + lane * 16;          // within A tile
    const int offB = 8192 + wn * 2048 + lane * 16;   // within B tile (Bs)

    #pragma unroll 1
    for (int kt = 0; kt < NK - 1; ++kt) {
        // ---------------- phase S ----------------
        asm volatile("s_waitcnt vmcnt(2)" ::: "memory");
        __builtin_amdgcn_s_barrier();
        u64x2 a01 = *(const u64x2*)(cur + offA);
        u64x2 a23 = *(const u64x2*)(cur + offA + 1024);
        u64x2 b01 = *(const u64x2*)(cur + offB);
        u64x2 b23 = *(const u64x2*)(cur + offB + 1024);
        gload16(gAs, nxt + sdst);
        gload16(gBs, nxt + 8192 + sdst);
        gAs += 1024; gBs += 1024;
        {
            long a[4] = {(long)a01[0], (long)a01[1], (long)a23[0], (long)a23[1]};
            long b[4] = {(long)b01[0], (long)b01[1], (long)b23[0], (long)b23[1]};
            __builtin_amdgcn_s_setprio(1);
            #pragma unroll
            for (int m = 0; m < 4; ++m)
                #pragma unroll
                for (int n = 0; n < 4; ++n)
                    acc_s[m][n] = __builtin_amdgcn_mfma_f32_16x16x32_fp8_fp8(a[m], b[n], acc_s[m][n], 0, 0, 0);
            __builtin_amdgcn_s_setprio(0);
        }

        // ---------------- phase T ----------------
        asm volatile("s_waitcnt vmcnt(2)" ::: "memory");
        __builtin_amdgcn_s_barrier();
        a01 = *(const u64x2*)(cur + 4096 + offA);
        a23 = *(const u64x2*)(cur + 4096 + offA + 1024);
        b01 = *(const u64x2*)(cur + 4096 + offB);
        b23 = *(const u64x2*)(cur + 4096 + offB + 1024);
        gload16(gAt, nxt + 4096 + sdst);
        gload16(gBt, nxt + 12288 + sdst);
        gAt += 1024; gBt += 1024;
        {
            long a[4] = {(long)a01[0], (long)a01[1], (long)a23[0], (long)a23[1]};
            long b[4] = {(long)b01[0], (long)b01[1], (long)b23[0], (long)b23[1]};
            __builtin_amdgcn_s_setprio(1);
            #pragma unroll
            for (int m = 0; m < 4; ++m)
                #pragma unroll
                for (int n = 0; n < 4; ++n)
                    acc_t[m][n] = __builtin_amdgcn_mfma_f32_16x16x32_fp8_fp8(a[m], b[n], acc_t[m][n], 0, 0, 0);
            __builtin_amdgcn_s_setprio(0);
        }

        char* tmp = cur; cur = nxt; nxt = tmp;
    }

    // peeled last K-step (outstanding: As,Bs,At,Bt of kt=NK-1)
    asm volatile("s_waitcnt vmcnt(2)" ::: "memory");
    __builtin_amdgcn_s_barrier();
    {
        u64x2 a01 = *(const u64x2*)(cur + offA);
        u64x2 a23 = *(const u64x2*)(cur + offA + 1024);
        u64x2 b01 = *(const u64x2*)(cur + offB);
        u64x2 b23 = *(const u64x2*)(cur + offB + 1024);
        long a[4] = {(long)a01[0], (long)a01[1], (long)a23[0], (long)a23[1]};
        long b[4] = {(long)b01[0], (long)b01[1], (long)b23[0], (long)b23[1]};
        __builtin_amdgcn_s_setprio(1);
        #pragma unroll
        for (int m = 0; m < 4; ++m)
            #pragma unroll
            for (int n = 0; n < 4; ++n)
                acc_s[m][n] = __builtin_amdgcn_mfma_f32_16x16x32_fp8_fp8(a[m], b[n], acc_s[m][n], 0, 0, 0);
        __builtin_amdgcn_s_setprio(0);
    }
    asm volatile("s_waitcnt vmcnt(0)" ::: "memory");
    __builtin_amdgcn_s_barrier();
    {
        u64x2 a01 = *(const u64x2*)(cur + 4096 + offA);
        u64x2 a23 = *(const u64x2*)(cur + 4096 + offA + 1024);
        u64x2 b01 = *(const u64x2*)(cur + 4096 + offB);
        u64x2 b23 = *(const u64x2*)(cur + 4096 + offB + 1024);
        long a[4] = {(long)a01[0], (long)a01[1], (long)a23[0], (long)a23[1]};
        long b[4] = {(long)b01[0], (long)b01[1], (long)b23[0], (long)b23[1]};
        __builtin_amdgcn_s_setprio(1);
        #pragma unroll
        for (int m = 0; m < 4; ++m)
            #pragma unroll
            for (int n = 0; n < 4; ++n)
                acc_t[m][n] = __builtin_amdgcn_mfma_f32_16x16x32_fp8_fp8(a[m], b[n], acc_t[m][n], 0, 0, 0);
        __builtin_amdgcn_s_setprio(0);
    }

    // ---- epilogue: per-row partial stats over this block's 128 columns ----
    __syncthreads();
    float* part = (float*)smem;      // [2 wn][128 rows][4 stats]
    int g = lane >> 4, cl = lane & 15;

    #pragma unroll
    for (int m = 0; m < 4; ++m) {
        float st[4][4];
        #pragma unroll
        for (int r = 0; r < 4; ++r) { st[r][0] = 0.f; st[r][1] = 0.f; st[r][2] = 0.f; st[r][3] = 0.f; }
        #pragma unroll
        for (int n = 0; n < 4; ++n)
            #pragma unroll
            for (int r = 0; r < 4; ++r) {
                float ls = 10.0f * acc_s[m][n][r];
                float lt = 10.0f * acc_t[m][n][r];
                float es = __expf(ls - 10.0f);
                float et = __expf(lt - 10.0f);
                st[r][0] += es;
                st[r][1] += et;
                st[r][2] += es * (ls - lt);
                st[r][3] += et * (lt - ls);
            }
        #pragma unroll
        for (int r = 0; r < 4; ++r)
            #pragma unroll
            for (int s = 0; s < 4; ++s) {
                float v = st[r][s];
                v += __shfl_xor(v, 1);
                v += __shfl_xor(v, 2);
                v += __shfl_xor(v, 4);
                v += __shfl_xor(v, 8);
                st[r][s] = v;
            }
        if (cl == 0) {
            int row = wm * 64 + m * 16 + g * 4;
            #pragma unroll
            for (int r = 0; r < 4; ++r)
                #pragma unroll
                for (int s = 0; s < 4; ++s)
                    part[(wn * 128 + row + r) * 4 + s] = st[r][s];
        }
    }
    __syncthreads();
    #pragma unroll
    for (int q = 0; q < 2; ++q) {
        int idx = t + q * 256;
        int row = idx >> 2, s = idx & 3;
        float v = part[(0 * 128 + row) * 4 + s] + part[(1 * 128 + row) * 4 + s];
        partial[((size_t)jb * N + (i0 + row)) * 4 + s] = v;
    }
}

// ---------------- per-row finalize + block partial sums ----------------------
__global__ __launch_bounds__(256) void reduce_rows(const float* __restrict__ partial,
                                                   float* __restrict__ blocksum) {
    int row = blockIdx.x * 256 + threadIdx.x;
    float zs = 0.f, zt = 0.f, ws = 0.f, wt = 0.f;
    for (int jb = 0; jb < 32; ++jb) {
        const float* p = partial + ((size_t)jb * N + row) * 4;
        zs += p[0]; zt += p[1]; ws += p[2]; wt += p[3];
    }
    float ls_row = wt / zt - logf(zt) + logf(zs);
    float lt_row = ws / zs - logf(zs) + logf(zt);
    #pragma unroll
    for (int m = 1; m < 64; m <<= 1) {
        ls_row += __shfl_xor(ls_row, m);
        lt_row += __shfl_xor(lt_row, m);
    }
    __shared__ float rs[4], rt[4];
    int lane = threadIdx.x & 63, wid = threadIdx.x >> 6;
    if (lane == 0) { rs[wid] = ls_row; rt[wid] = lt_row; }
    __syncthreads();
    if (threadIdx.x == 0) {
        blocksum[blockIdx.x * 2]     = rs[0] + rs[1] + rs[2] + rs[3];
        blocksum[blockIdx.x * 2 + 1] = rt[0] + rt[1] + rt[2] + rt[3];
    }
}

__global__ void final_reduce(const float* __restrict__ blocksum, float* __restrict__ out) {
    float a = 0.f, b = 0.f;
    if (threadIdx.x < 16) { a = blocksum[threadIdx.x * 2]; b = blocksum[threadIdx.x * 2 + 1]; }
    #pragma unroll
    for (int m = 1; m < 16; m <<= 1) { a += __shfl_xor(a, m); b += __shfl_xor(b, m); }
    if (threadIdx.x == 0) {
        const float inv = 1.0f / 16777216.0f;   // 1/N^2
        out[0] = a * inv;
        out[1] = b * inv;
    }
}

extern "C" void kernel_launch(void* const* d_in, const int* in_sizes, int n_in,
                              void* d_out, int out_size, void* d_ws, size_t ws_size,
                              hipStream_t stream) {
    const float* zxs = (const float*)d_in[0];
    const float* zys = (const float*)d_in[1];
    const float* zxt = (const float*)d_in[2];
    const float* zyt = (const float*)d_in[3];

    char* ws = (char*)d_ws;
    const size_t A = (size_t)N * D;                   // bytes per fp8 array
    unsigned char* nb = (unsigned char*)ws;           // 4 normalized fp8 arrays (tiled)
    float* partial  = (float*)(ws + 4 * A);           // [32][N][4] f32 = 2 MB
    float* blocksum = (float*)(ws + 4 * A + (size_t)32 * N * 4 * sizeof(float));

    norm4<<<dim3(N / 32, 4), 256, 0, stream>>>(zxs, zys, zxt, zyt, nb);

    const unsigned char* Xs = nb;
    const unsigned char* Ys = nb + A;
    const unsigned char* Xt = nb + 2 * A;
    const unsigned char* Yt = nb + 3 * A;
    fused_gemm<<<dim3(32, 32), 256, 0, stream>>>(Xs, Ys, Xt, Yt, partial);

    reduce_rows<<<16, 256, 0, stream>>>(partial, blocksum);
    final_reduce<<<1, 64, 0, stream>>>(blocksum, (float*)d_out);
}